// Round 12
// baseline (96499.426 us; speedup 1.0000x reference)
//
#include <hip/hip_runtime.h>
#include <math.h>

#define N_NODES 50000
#define N_EDGES 1600000
#define DIN 1024
#define H 256
#define L_LAYERS 64
#define ALPHA 0.2f
#define NCHUNK 8            // feature chunks: 32 cols = 64 B each
#define CCOLS 32
#define NBLK 3125           // node-blocks of 16 (3125*16 == 50000 exactly)
#define SPMM_IDX (NBLK * NCHUNK)        // 25000 spmm work items
#define GEMM_BLKS (391 * 2)             // 391 row-tiles x 2 col-halves = 782
#define INTERLEAVE 33                   // 32 spmm : 1 gemm
#define NTILES 391                      // 128-row tiles

typedef unsigned short u16;                                   // bf16 storage
typedef short short8 __attribute__((ext_vector_type(8)));     // MFMA A/B frag (8 bf16)
typedef unsigned short ushort8_t __attribute__((ext_vector_type(8)));
typedef float f32x4 __attribute__((ext_vector_type(4)));      // MFMA C/D frag
typedef float f32x2 __attribute__((ext_vector_type(2)));      // packed f32 (v_pk_fma_f32)
typedef unsigned int u32x4 __attribute__((ext_vector_type(4)));

__device__ inline float b2f(u16 h) { return __uint_as_float(((unsigned)h) << 16); }
__device__ inline u16 f2b(float f) {
  unsigned u = __float_as_uint(f);
  unsigned r = u + 0x7FFFu + ((u >> 16) & 1u);   // round-to-nearest-even
  return (u16)(r >> 16);
}

// unpack one u32 (2 bf16) into packed f32 pair {lo, hi}
__device__ inline f32x2 bp2f(unsigned u) {
  f32x2 p;
  p[0] = __uint_as_float(u << 16);
  p[1] = __uint_as_float(u & 0xFFFF0000u);
  return p;
}

// blocked bf16 feature layout: X[chunk][node][32], chunk = col>>5
__device__ inline size_t bidx(int node, int col) {
  return ((size_t)(col >> 5) * N_NODES + node) * CCOLS + (col & 31);
}

// Keep a symbol with the exact problem identifier.
__global__ void GCNIIForDialog_18923625906417_kernel() {}

// ---------- utility: zero ints ----------
__global__ __launch_bounds__(256) void k_zero(int* __restrict__ p, int n) {
  int i = blockIdx.x * 256 + threadIdx.x;
  if (i < n) p[i] = 0;
}

// ---------- graph build ----------
__global__ __launch_bounds__(256) void k_count(const int* __restrict__ dst, int* __restrict__ cnt) {
  int e = blockIdx.x * 256 + threadIdx.x;
  if (e < N_EDGES) atomicAdd(&cnt[dst[e]], 1);
}

__global__ __launch_bounds__(256) void k_dinv(const int* __restrict__ cnt, float* __restrict__ dinv) {
  int i = blockIdx.x * 256 + threadIdx.x;
  if (i < N_NODES) dinv[i] = 1.0f / sqrtf((float)(cnt[i] + 1));  // +1 self loop
}

__global__ __launch_bounds__(1024) void k_scan(const int* __restrict__ cnt, int* __restrict__ offs) {
  const int CH = (N_NODES + 1023) / 1024;  // 49
  __shared__ int sums[1024];
  int t = threadIdx.x;
  int lo = t * CH, hi = lo + CH;
  if (hi > N_NODES) hi = N_NODES;
  int s = 0;
  for (int i = lo; i < hi; ++i) s += cnt[i];
  sums[t] = s;
  __syncthreads();
  for (int d = 1; d < 1024; d <<= 1) {
    int v = (t >= d) ? sums[t - d] : 0;
    __syncthreads();
    sums[t] += v;
    __syncthreads();
  }
  int run = (t == 0) ? 0 : sums[t - 1];
  for (int i = lo; i < hi; ++i) { offs[i] = run; run += cnt[i]; }
  if (t == 0) offs[N_NODES] = sums[1023];
}

// edge record: 4 B packed {bf16 w | u16 col}  (N_NODES < 65536 so col fits u16)
__global__ __launch_bounds__(256) void k_scatter(const int* __restrict__ src, const int* __restrict__ dst,
    const int* __restrict__ offs, int* __restrict__ cursor, const float* __restrict__ dinv,
    unsigned* __restrict__ ew) {
  int e = blockIdx.x * 256 + threadIdx.x;
  if (e >= N_EDGES) return;
  int sN = src[e], dN = dst[e];
  int pos = offs[dN] + atomicAdd(&cursor[dN], 1);
  unsigned wb = (unsigned)f2b(dinv[sN] * dinv[dN]);
  ew[pos] = (wb << 16) | (unsigned)sN;
}

// ---------- W prep: WT[l][n][k] = (bf16) W[l][k][n] ----------
__global__ void k_wtr(const float* __restrict__ Win, u16* __restrict__ Wout) {
  __shared__ float tile[32][33];
  size_t base = (size_t)blockIdx.z * H * H;
  int n0 = blockIdx.x * 32, k0 = blockIdx.y * 32;
  for (int i = threadIdx.y; i < 32; i += 8)
    tile[i][threadIdx.x] = Win[base + (size_t)(k0 + i) * H + n0 + threadIdx.x];
  __syncthreads();
  for (int i = threadIdx.y; i < 32; i += 8)
    Wout[base + (size_t)(n0 + i) * H + k0 + threadIdx.x] = f2b(tile[threadIdx.x][i]);
}

// ---------- projW prep: BTp[n][k] = (bf16) projW[k][n], [256][1024] ----------
__global__ void k_trP(const float* __restrict__ Win, u16* __restrict__ Wout) {
  __shared__ float tile[32][33];
  int n0 = blockIdx.x * 32, k0 = blockIdx.y * 32;   // n over 256, k over 1024
  for (int i = threadIdx.y; i < 32; i += 8)
    tile[i][threadIdx.x] = Win[(size_t)(k0 + i) * H + n0 + threadIdx.x];
  __syncthreads();
  for (int i = threadIdx.y; i < 32; i += 8)
    Wout[(size_t)(n0 + i) * DIN + k0 + threadIdx.x] = f2b(tile[threadIdx.x][i]);
}

// ---------- FUSED layer: interleaved SpMM producers + GEMM consumers ----------
// Grid = 782*33 blocks. Pattern: 32 spmm work-items then 1 gemm block, repeating.
// spmm item sidx: chunk = sidx&7, nb = sidx>>3 (16 nodes); on completion:
// threadfence + atomicAdd(cnt[nb>>3]). gemm block g: row-tile g>>1, col-half g&1;
// spins until cnt[tile] reaches 8 chunks x nb-blocks, then runs the 128x128 MFMA GEMM.
// Deadlock-free for ANY dispatch order: launch_bounds(256,4) => >=1024 resident
// blocks > 782 total spinners, so spmm always has slots to progress.
// NOTE: hin and hout must be distinct buffers (gemm overwrites while spmm gathers).
__global__ __launch_bounds__(256, 4) void k_layer(
    const u16* __restrict__ hin, const u16* __restrict__ h0b,
    const int* __restrict__ offs, const unsigned* __restrict__ ew,
    const float* __restrict__ dinv, u16* __restrict__ sbb,
    const u16* __restrict__ BT, u16* __restrict__ hout,
    int* __restrict__ cnt, float beta)
{
  __shared__ u16 As[128 * 40];   // gemm staging (20.5 KB total -> 7 blocks/CU by LDS)
  __shared__ u16 Bs[128 * 40];
  int g = blockIdx.x / INTERLEAVE;
  int r = blockIdx.x % INTERLEAVE;
  int tid = threadIdx.x;

  if (r < 32) {
    // ================= SpMM producer =================
    int sidx = g * 32 + r;
    if (sidx >= SPMM_IDX) return;
    int chunk = sidx & 7;
    int nb = sidx >> 3;            // 16 nodes: nb*16 .. nb*16+15 (always < 50000)
    int wid = tid >> 6, lane = tid & 63;
    int sub = lane & 3;            // 16B subchunk within the 64B row
    int eslot = (lane >> 2) & 3;   // edge slot 0..3
    int nsub = lane >> 4;          // node within wave 0..3
    int node = nb * 16 + wid * 4 + nsub;
    const u16* hc = hin + (size_t)chunk * N_NODES * CCOLS;
    const u16* hp = hc + sub * 8;
    f32x2 acc2[4] = {};
    int end = offs[node + 1];
    int i = offs[node] + eslot;
    for (; i + 12 < end; i += 16) {   // 4 edges per slot in flight
      unsigned e0 = ew[i];
      unsigned e1 = ew[i + 4];
      unsigned e2 = ew[i + 8];
      unsigned e3 = ew[i + 12];
      u32x4 v0 = *(const u32x4*)(hp + (size_t)(e0 & 0xFFFFu) * CCOLS);
      u32x4 v1 = *(const u32x4*)(hp + (size_t)(e1 & 0xFFFFu) * CCOLS);
      u32x4 v2 = *(const u32x4*)(hp + (size_t)(e2 & 0xFFFFu) * CCOLS);
      u32x4 v3 = *(const u32x4*)(hp + (size_t)(e3 & 0xFFFFu) * CCOLS);
      float w0 = __uint_as_float(e0 & 0xFFFF0000u);
      float w1 = __uint_as_float(e1 & 0xFFFF0000u);
      float w2 = __uint_as_float(e2 & 0xFFFF0000u);
      float w3 = __uint_as_float(e3 & 0xFFFF0000u);
      f32x2 w0v = {w0, w0}, w1v = {w1, w1}, w2v = {w2, w2}, w3v = {w3, w3};
#pragma unroll
      for (int j = 0; j < 4; ++j) acc2[j] += w0v * bp2f(v0[j]);
#pragma unroll
      for (int j = 0; j < 4; ++j) acc2[j] += w1v * bp2f(v1[j]);
#pragma unroll
      for (int j = 0; j < 4; ++j) acc2[j] += w2v * bp2f(v2[j]);
#pragma unroll
      for (int j = 0; j < 4; ++j) acc2[j] += w3v * bp2f(v3[j]);
    }
    for (; i < end; i += 4) {
      unsigned e0 = ew[i];
      u32x4 v0 = *(const u32x4*)(hp + (size_t)(e0 & 0xFFFFu) * CCOLS);
      float w0 = __uint_as_float(e0 & 0xFFFF0000u);
      f32x2 w0v = {w0, w0};
#pragma unroll
      for (int j = 0; j < 4; ++j) acc2[j] += w0v * bp2f(v0[j]);
    }
    // reduce across the 4 edge slots (lane bits 2,3)
#pragma unroll
    for (int d = 4; d <= 8; d <<= 1)
#pragma unroll
      for (int j = 0; j < 4; ++j) {
        acc2[j][0] += __shfl_xor(acc2[j][0], d);
        acc2[j][1] += __shfl_xor(acc2[j][1], d);
      }
    if (eslot == 0) {              // 16 lanes write 4 consecutive 64B rows
      float di = dinv[node];
      float di2 = di * di;
      size_t ci = (size_t)chunk * N_NODES * CCOLS + (size_t)node * CCOLS + sub * 8;
      ushort8_t hv = *(const ushort8_t*)(hp + (size_t)node * CCOLS);   // self loop
      ushort8_t h0v = __builtin_nontemporal_load((const ushort8_t*)(h0b + ci));
      ushort8_t o;
#pragma unroll
      for (int j = 0; j < 4; ++j) {
#pragma unroll
        for (int c = 0; c < 2; ++c) {
          int k = 2 * j + c;
          float v = (1.0f - ALPHA) * (acc2[j][c] + di2 * b2f(hv[k])) + ALPHA * b2f(h0v[k]);
          o[k] = f2b(v);
        }
      }
      *(ushort8_t*)(sbb + ci) = o;   // plain coherent store (fenced below)
    }
    __syncthreads();
    if (tid == 0) {
      __threadfence();               // publish sb stores device-wide
      atomicAdd(&cnt[nb >> 3], 1);   // signal this (nb, chunk) contribution
    }
    return;
  }

  // ================= GEMM consumer =================
  if (g >= GEMM_BLKS) return;
  int tile = g >> 1;               // 128-row tile
  int mBase = tile * 128, nBase = (g & 1) * 128;
  int nbs = NBLK - tile * 8; if (nbs > 8) nbs = 8;
  int expected = nbs * 8;          // nb-blocks x 8 chunks
  if (tid == 0) {
    while (__hip_atomic_load(&cnt[tile], __ATOMIC_ACQUIRE, __HIP_MEMORY_SCOPE_AGENT) < expected)
      __builtin_amdgcn_s_sleep(2);
    __threadfence();
  }
  __syncthreads();                 // all threads see sb rows mBase..mBase+127

  int wid = tid >> 6, lane = tid & 63;
  int wm = (wid & 1) * 64, wn = (wid >> 1) * 64;
  int lrow = lane & 15, quad = lane >> 4;
  f32x4 acc[4][4] = {};
  int sr = tid >> 2, sc = tid & 3;
  for (int k0 = 0; k0 < H; k0 += 32) {
    const u16* Ac = sbb + (size_t)(k0 >> 5) * N_NODES * CCOLS;
#pragma unroll
    for (int it = 0; it < 2; ++it) {
      int rr = sr + it * 64;
      int grow = mBase + rr;
      u32x4 va = {};
      if (grow < N_NODES) va = *(const u32x4*)(Ac + (size_t)grow * CCOLS + sc * 8);
      *(u32x4*)&As[rr * 40 + sc * 8] = va;
      u32x4 vb = *(const u32x4*)(BT + (size_t)(nBase + rr) * H + k0 + sc * 8);
      *(u32x4*)&Bs[rr * 40 + sc * 8] = vb;
    }
    __syncthreads();
    short8 af[4], bfr[4];
#pragma unroll
    for (int i = 0; i < 4; ++i) {
      af[i]  = *(const short8*)&As[(wm + i * 16 + lrow) * 40 + quad * 8];
      bfr[i] = *(const short8*)&Bs[(wn + i * 16 + lrow) * 40 + quad * 8];
    }
#pragma unroll
    for (int mi = 0; mi < 4; ++mi)
#pragma unroll
      for (int ni = 0; ni < 4; ++ni)
        acc[mi][ni] = __builtin_amdgcn_mfma_f32_16x16x32_bf16(af[mi], bfr[ni], acc[mi][ni], 0, 0, 0);
    __syncthreads();
  }
#pragma unroll
  for (int mi = 0; mi < 4; ++mi)
#pragma unroll
    for (int ni = 0; ni < 4; ++ni)
#pragma unroll
      for (int rg = 0; rg < 4; ++rg) {
        int rr = mBase + wm + mi * 16 + quad * 4 + rg;  // C/D: row = quad*4+reg
        int c = nBase + wn + ni * 16 + lrow;            //      col = lane&15
        if (rr < N_NODES) {
          size_t idx = bidx(rr, c);
          float v = (1.0f - beta) * b2f(sbb[idx]) + beta * acc[mi][ni][rg];
          hout[idx] = f2b(fmaxf(v, 0.0f));
        }
      }
}

// ---------- projection MFMA GEMM: h0b = h = bf16(x @ projW + b), K=1024 ----------
// 64-row M-tile (grid 782x2 = 1564 blocks, 6/CU). Waves 1x4 over columns.
__global__ __launch_bounds__(256) void k_pgemm(
    const float* __restrict__ X, const u16* __restrict__ BT,
    const float* __restrict__ bias, u16* __restrict__ h0b, u16* __restrict__ h)
{
  __shared__ u16 As[64 * 40];
  __shared__ u16 Bs[128 * 40];
  int tid = threadIdx.x;
  int mBase = blockIdx.x * 64, nBase = blockIdx.y * 128;
  int wid = tid >> 6, lane = tid & 63;
  int wn = wid * 32;               // wave covers cols wn..wn+31 of the 128-col tile
  int lrow = lane & 15, quad = lane >> 4;
  f32x4 acc[4][2] = {};
  int sr = tid >> 2, sc = tid & 3;
  for (int k0 = 0; k0 < DIN; k0 += 32) {
    {   // stage A: 64 rows x 32 k (one pass)
      int grow = mBase + sr;
      float4 fa0 = make_float4(0.f, 0.f, 0.f, 0.f);
      float4 fa1 = make_float4(0.f, 0.f, 0.f, 0.f);
      if (grow < N_NODES) {
        const float* ap = X + (size_t)grow * DIN + k0 + sc * 8;
        fa0 = *(const float4*)ap;
        fa1 = *(const float4*)(ap + 4);
      }
      ushort8_t av;
      av[0] = f2b(fa0.x); av[1] = f2b(fa0.y); av[2] = f2b(fa0.z); av[3] = f2b(fa0.w);
      av[4] = f2b(fa1.x); av[5] = f2b(fa1.y); av[6] = f2b(fa1.z); av[7] = f2b(fa1.w);
      *(ushort8_t*)&As[sr * 40 + sc * 8] = av;
    }
#pragma unroll
    for (int it = 0; it < 2; ++it) {   // stage B: 128 n-rows x 32 k
      int r = sr + it * 64;
      u32x4 vb = *(const u32x4*)(BT + (size_t)(nBase + r) * DIN + k0 + sc * 8);
      *(u32x4*)&Bs[r * 40 + sc * 8] = vb;
    }
    __syncthreads();
    short8 af[4], bfr[2];
#pragma unroll
    for (int i = 0; i < 4; ++i)
      af[i] = *(const short8*)&As[(i * 16 + lrow) * 40 + quad * 8];
#pragma unroll
    for (int i = 0; i < 2; ++i)
      bfr[i] = *(const short8*)&Bs[(wn + i * 16 + lrow) * 40 + quad * 8];
#pragma unroll
    for (int mi = 0; mi < 4; ++mi)
#pragma unroll
      for (int ni = 0; ni < 2; ++ni)
        acc[mi][ni] = __builtin_amdgcn_mfma_f32_16x16x32_bf16(af[mi], bfr[ni], acc[mi][ni], 0, 0, 0);
    __syncthreads();
  }
#pragma unroll
  for (int mi = 0; mi < 4; ++mi)
#pragma unroll
    for (int ni = 0; ni < 2; ++ni)
#pragma unroll
      for (int rg = 0; rg < 4; ++rg) {
        int r = mBase + mi * 16 + quad * 4 + rg;       // C/D: row = quad*4+reg
        int c = nBase + wn + ni * 16 + lrow;           //      col = lane&15
        if (r < N_NODES) {
          size_t idx = bidx(r, c);
          float v = acc[mi][ni][rg] + bias[c];
          u16 bv = f2b(v);
          h0b[idx] = bv;
          h[idx] = bv;
        }
      }
}

// ---------- classifier: out[n, 0..3] = h[n,:] @ clsW + clsb (h blocked bf16) ----------
__global__ __launch_bounds__(256) void k_cls(const u16* __restrict__ h,
    const float* __restrict__ W, const float* __restrict__ b, float* __restrict__ out)
{
  int wid = threadIdx.x >> 6, lane = threadIdx.x & 63;
  int node = blockIdx.x * 4 + wid;
  if (node >= N_NODES) return;
  float a0 = 0, a1 = 0, a2 = 0, a3 = 0;
  for (int t = lane; t < H; t += 64) {
    float hv = b2f(h[bidx(node, t)]);
    a0 += hv * W[t * 4 + 0];
    a1 += hv * W[t * 4 + 1];
    a2 += hv * W[t * 4 + 2];
    a3 += hv * W[t * 4 + 3];
  }
#pragma unroll
  for (int off = 32; off > 0; off >>= 1) {
    a0 += __shfl_down(a0, off);
    a1 += __shfl_down(a1, off);
    a2 += __shfl_down(a2, off);
    a3 += __shfl_down(a3, off);
  }
  if (lane == 0) {
    float4 o;
    o.x = a0 + b[0];
    o.y = a1 + b[1];
    o.z = a2 + b[2];
    o.w = a3 + b[3];
    *(float4*)(out + (size_t)node * 4) = o;
  }
}

extern "C" void kernel_launch(void* const* d_in, const int* in_sizes, int n_in,
                              void* d_out, int out_size, void* d_ws, size_t ws_size,
                              hipStream_t stream) {
  (void)in_sizes; (void)n_in; (void)out_size; (void)ws_size;
  const float* x     = (const float*)d_in[0];
  const int*   ei    = (const int*)d_in[1];
  const float* projW = (const float*)d_in[2];
  const float* projB = (const float*)d_in[3];
  const float* wts   = (const float*)d_in[4];
  const float* clsW  = (const float*)d_in[5];
  const float* clsB  = (const float*)d_in[6];
  float* out = (float*)d_out;

  char* ws = (char*)d_ws;
  size_t off = 0;
  auto alloc = [&](size_t bytes) -> void* {
    void* p = ws + off;
    off = (off + bytes + 255) & ~(size_t)255;
    return p;
  };
  int*   cntcur = (int*)alloc((size_t)N_NODES * 2 * 4);
  int*   cnt    = cntcur;
  int*   cursor = cntcur + N_NODES;
  int*   offs   = (int*)alloc((size_t)(N_NODES + 1) * 4);
  float* dinv   = (float*)alloc((size_t)N_NODES * 4);
  unsigned* ew  = (unsigned*)alloc((size_t)N_EDGES * 4);
  int*   tcnt   = (int*)alloc((size_t)L_LAYERS * NTILES * 4);   // per-layer tile counters
  u16*   WT     = (u16*)alloc((size_t)L_LAYERS * H * H * 2);
  u16*   BTp    = (u16*)alloc((size_t)H * DIN * 2);
  u16*   h0b    = (u16*)alloc((size_t)N_NODES * H * 2);
  u16*   sb     = (u16*)alloc((size_t)N_NODES * H * 2);
  u16*   hA     = (u16*)alloc((size_t)N_NODES * H * 2);
  u16*   hB     = (u16*)alloc((size_t)N_NODES * H * 2);

  const int* src = ei;
  const int* dst = ei + N_EDGES;

  k_zero<<<(N_NODES * 2 + 255) / 256, 256, 0, stream>>>(cntcur, N_NODES * 2);
  k_zero<<<(L_LAYERS * NTILES + 255) / 256, 256, 0, stream>>>(tcnt, L_LAYERS * NTILES);
  k_count<<<(N_EDGES + 255) / 256, 256, 0, stream>>>(dst, cnt);
  k_dinv<<<(N_NODES + 255) / 256, 256, 0, stream>>>(cnt, dinv);
  k_scan<<<1, 1024, 0, stream>>>(cnt, offs);
  k_scatter<<<(N_EDGES + 255) / 256, 256, 0, stream>>>(src, dst, offs, cursor, dinv, ew);
  k_wtr<<<dim3(H / 32, H / 32, L_LAYERS), dim3(32, 8), 0, stream>>>(wts, WT);
  k_trP<<<dim3(H / 32, DIN / 32), dim3(32, 8), 0, stream>>>(projW, BTp);

  // projection: h0b (bf16) and hA (bf16) = bf16(x @ projW + b), via MFMA
  k_pgemm<<<dim3((N_NODES + 63) / 64, H / 128), 256, 0, stream>>>(x, BTp, projB, h0b, hA);

  const int lgrid = GEMM_BLKS * INTERLEAVE;   // 782*33 = 25806
  for (int l = 0; l < L_LAYERS; ++l) {
    const u16* hin = (l & 1) ? hB : hA;
    u16* hout      = (l & 1) ? hA : hB;
    float beta = logf(0.5f / (float)(l + 1) + 1.0f);
    k_layer<<<lgrid, 256, 0, stream>>>(hin, h0b, offs, ew, dinv, sb,
                                       WT + (size_t)l * H * H, hout,
                                       tcnt + (size_t)l * NTILES, beta);
  }
  // after 64 layers (even), final output is in hA
  k_cls<<<(N_NODES + 3) / 4, 256, 0, stream>>>(hA, clsW, clsB, out);
}

// Round 13
// 9369.205 us; speedup vs baseline: 10.2996x; 10.2996x over previous
//
#include <hip/hip_runtime.h>
#include <math.h>

#define N_NODES 50000
#define N_EDGES 1600000
#define DIN 1024
#define H 256
#define L_LAYERS 64
#define ALPHA 0.2f
#define NCHUNK 8            // feature chunks: 32 cols = 64 B each
#define CCOLS 32

typedef unsigned short u16;                                   // bf16 storage
typedef short short8 __attribute__((ext_vector_type(8)));     // MFMA A/B frag (8 bf16)
typedef unsigned short ushort8_t __attribute__((ext_vector_type(8)));
typedef float f32x4 __attribute__((ext_vector_type(4)));      // MFMA C/D frag
typedef float f32x2 __attribute__((ext_vector_type(2)));      // packed f32 (v_pk_fma_f32)
typedef unsigned int u32x4 __attribute__((ext_vector_type(4)));

__device__ inline float b2f(u16 h) { return __uint_as_float(((unsigned)h) << 16); }
__device__ inline u16 f2b(float f) {
  unsigned u = __float_as_uint(f);
  unsigned r = u + 0x7FFFu + ((u >> 16) & 1u);   // round-to-nearest-even
  return (u16)(r >> 16);
}

// unpack one u32 (2 bf16) into packed f32 pair {lo, hi}
__device__ inline f32x2 bp2f(unsigned u) {
  f32x2 p;
  p[0] = __uint_as_float(u << 16);
  p[1] = __uint_as_float(u & 0xFFFF0000u);
  return p;
}

// blocked bf16 feature layout: X[chunk][node][32], chunk = col>>5
__device__ inline size_t bidx(int node, int col) {
  return ((size_t)(col >> 5) * N_NODES + node) * CCOLS + (col & 31);
}

// Keep a symbol with the exact problem identifier.
__global__ void GCNIIForDialog_18923625906417_kernel() {}

// ---------- utility: zero ints ----------
__global__ __launch_bounds__(256) void k_zero(int* __restrict__ p, int n) {
  int i = blockIdx.x * 256 + threadIdx.x;
  if (i < n) p[i] = 0;
}

// ---------- graph build ----------
__global__ __launch_bounds__(256) void k_count(const int* __restrict__ dst, int* __restrict__ cnt) {
  int e = blockIdx.x * 256 + threadIdx.x;
  if (e < N_EDGES) atomicAdd(&cnt[dst[e]], 1);
}

__global__ __launch_bounds__(256) void k_dinv(const int* __restrict__ cnt, float* __restrict__ dinv) {
  int i = blockIdx.x * 256 + threadIdx.x;
  if (i < N_NODES) dinv[i] = 1.0f / sqrtf((float)(cnt[i] + 1));  // +1 self loop
}

__global__ __launch_bounds__(1024) void k_scan(const int* __restrict__ cnt, int* __restrict__ offs) {
  const int CH = (N_NODES + 1023) / 1024;  // 49
  __shared__ int sums[1024];
  int t = threadIdx.x;
  int lo = t * CH, hi = lo + CH;
  if (hi > N_NODES) hi = N_NODES;
  int s = 0;
  for (int i = lo; i < hi; ++i) s += cnt[i];
  sums[t] = s;
  __syncthreads();
  for (int d = 1; d < 1024; d <<= 1) {
    int v = (t >= d) ? sums[t - d] : 0;
    __syncthreads();
    sums[t] += v;
    __syncthreads();
  }
  int run = (t == 0) ? 0 : sums[t - 1];
  for (int i = lo; i < hi; ++i) { offs[i] = run; run += cnt[i]; }
  if (t == 0) offs[N_NODES] = sums[1023];
}

// edge record: 4 B packed {bf16 w | u16 col}  (N_NODES < 65536 so col fits u16)
__global__ __launch_bounds__(256) void k_scatter(const int* __restrict__ src, const int* __restrict__ dst,
    const int* __restrict__ offs, int* __restrict__ cursor, const float* __restrict__ dinv,
    unsigned* __restrict__ ew) {
  int e = blockIdx.x * 256 + threadIdx.x;
  if (e >= N_EDGES) return;
  int sN = src[e], dN = dst[e];
  int pos = offs[dN] + atomicAdd(&cursor[dN], 1);
  unsigned wb = (unsigned)f2b(dinv[sN] * dinv[dN]);
  ew[pos] = (wb << 16) | (unsigned)sN;
}

// ---------- W prep: WT[l][n][k] = (bf16) W[l][k][n] ----------
__global__ void k_wtr(const float* __restrict__ Win, u16* __restrict__ Wout) {
  __shared__ float tile[32][33];
  size_t base = (size_t)blockIdx.z * H * H;
  int n0 = blockIdx.x * 32, k0 = blockIdx.y * 32;
  for (int i = threadIdx.y; i < 32; i += 8)
    tile[i][threadIdx.x] = Win[base + (size_t)(k0 + i) * H + n0 + threadIdx.x];
  __syncthreads();
  for (int i = threadIdx.y; i < 32; i += 8)
    Wout[base + (size_t)(n0 + i) * H + k0 + threadIdx.x] = f2b(tile[threadIdx.x][i]);
}

// ---------- projW prep: BTp[n][k] = (bf16) projW[k][n], [256][1024] ----------
__global__ void k_trP(const float* __restrict__ Win, u16* __restrict__ Wout) {
  __shared__ float tile[32][33];
  int n0 = blockIdx.x * 32, k0 = blockIdx.y * 32;   // n over 256, k over 1024
  for (int i = threadIdx.y; i < 32; i += 8)
    tile[i][threadIdx.x] = Win[(size_t)(k0 + i) * H + n0 + threadIdx.x];
  __syncthreads();
  for (int i = threadIdx.y; i < 32; i += 8)
    Wout[(size_t)(n0 + i) * DIN + k0 + threadIdx.x] = f2b(tile[threadIdx.x][i]);
}

// ---------- SpMM + residual, feature-chunked (r6 optimum, unchanged) ----------
// chunk = blockIdx.x & 7; wave handles 4 consecutive nodes: lane = (nsub:2|eslot:2|sub:2).
// 16 lanes per node (4 edge slots x 4x16B subchunks); 2-stage shuffle reduce.
// Main loop: 4 edges per slot in flight; 4B edge records; NT on touch-once streams.
__global__ __launch_bounds__(256) void k_spmm(
    const u16* __restrict__ hb, const u16* __restrict__ h0b,
    const int* __restrict__ offs, const unsigned* __restrict__ ew,
    const float* __restrict__ dinv, u16* __restrict__ sbb)
{
  int bid = blockIdx.x;
  int chunk = bid & 7;
  int nb = bid >> 3;               // node-block: 16 nodes (4 waves x 4 nodes)
  int wid = threadIdx.x >> 6, lane = threadIdx.x & 63;
  int sub = lane & 3;              // 16B subchunk within the 64B row
  int eslot = (lane >> 2) & 3;     // edge slot 0..3
  int nsub = lane >> 4;            // node within wave 0..3
  int node = nb * 16 + wid * 4 + nsub;
  if (node >= N_NODES) return;
  const u16* hc = hb + (size_t)chunk * N_NODES * CCOLS;
  const u16* hp = hc + sub * 8;
  f32x2 acc2[4] = {};
  int end = offs[node + 1];
  int i = offs[node] + eslot;
  // main: 4 edges per slot per iteration (16 edges/node/iter), 4 gathers in flight
  for (; i + 12 < end; i += 16) {
    unsigned e0 = ew[i];
    unsigned e1 = ew[i + 4];
    unsigned e2 = ew[i + 8];
    unsigned e3 = ew[i + 12];
    u32x4 v0 = *(const u32x4*)(hp + (size_t)(e0 & 0xFFFFu) * CCOLS);
    u32x4 v1 = *(const u32x4*)(hp + (size_t)(e1 & 0xFFFFu) * CCOLS);
    u32x4 v2 = *(const u32x4*)(hp + (size_t)(e2 & 0xFFFFu) * CCOLS);
    u32x4 v3 = *(const u32x4*)(hp + (size_t)(e3 & 0xFFFFu) * CCOLS);
    float w0 = __uint_as_float(e0 & 0xFFFF0000u);
    float w1 = __uint_as_float(e1 & 0xFFFF0000u);
    float w2 = __uint_as_float(e2 & 0xFFFF0000u);
    float w3 = __uint_as_float(e3 & 0xFFFF0000u);
    f32x2 w0v = {w0, w0}, w1v = {w1, w1}, w2v = {w2, w2}, w3v = {w3, w3};
#pragma unroll
    for (int j = 0; j < 4; ++j) acc2[j] += w0v * bp2f(v0[j]);
#pragma unroll
    for (int j = 0; j < 4; ++j) acc2[j] += w1v * bp2f(v1[j]);
#pragma unroll
    for (int j = 0; j < 4; ++j) acc2[j] += w2v * bp2f(v2[j]);
#pragma unroll
    for (int j = 0; j < 4; ++j) acc2[j] += w3v * bp2f(v3[j]);
  }
  // tail: 1 edge per slot per iteration
  for (; i < end; i += 4) {
    unsigned e0 = ew[i];
    u32x4 v0 = *(const u32x4*)(hp + (size_t)(e0 & 0xFFFFu) * CCOLS);
    float w0 = __uint_as_float(e0 & 0xFFFF0000u);
    f32x2 w0v = {w0, w0};
#pragma unroll
    for (int j = 0; j < 4; ++j) acc2[j] += w0v * bp2f(v0[j]);
  }
  // reduce across the 4 edge slots (lane bits 2,3); partners share nsub & sub
#pragma unroll
  for (int d = 4; d <= 8; d <<= 1)
#pragma unroll
    for (int j = 0; j < 4; ++j) {
      acc2[j][0] += __shfl_xor(acc2[j][0], d);
      acc2[j][1] += __shfl_xor(acc2[j][1], d);
    }
  if (eslot == 0) {                // 16 lanes write 4 consecutive 64B rows
    float di = dinv[node];
    float di2 = di * di;
    size_t ci = (size_t)chunk * N_NODES * CCOLS + (size_t)node * CCOLS + sub * 8;
    ushort8_t hv = *(const ushort8_t*)(hp + (size_t)node * CCOLS);   // self loop (hot set)
    ushort8_t h0v = __builtin_nontemporal_load((const ushort8_t*)(h0b + ci));  // touch-once
    ushort8_t o;
#pragma unroll
    for (int j = 0; j < 4; ++j) {
#pragma unroll
      for (int c = 0; c < 2; ++c) {
        int k = 2 * j + c;
        float v = (1.0f - ALPHA) * (acc2[j][c] + di2 * b2f(hv[k])) + ALPHA * b2f(h0v[k]);
        o[k] = f2b(v);
      }
    }
    __builtin_nontemporal_store(o, (ushort8_t*)(sbb + ci));          // touch-once
  }
}

// ---------- MFMA layer GEMM: h = relu((1-beta)*sb + beta * (sb @ W)) ----------
// A = sb in blocked layout [8][N][32]; BT = WT_l [256,256] bf16, BT[n][k] = W[k][n].
__global__ __launch_bounds__(256) void k_gemm(
    const u16* __restrict__ A, const u16* __restrict__ BT,
    u16* __restrict__ Hout, float beta)
{
  __shared__ u16 As[128 * 40];  // row stride 40 u16 = 80 B
  __shared__ u16 Bs[128 * 40];
  int tid = threadIdx.x;
  int mBase = blockIdx.x * 128, nBase = blockIdx.y * 128;
  int wid = tid >> 6, lane = tid & 63;
  int wm = (wid & 1) * 64, wn = (wid >> 1) * 64;
  int lrow = lane & 15, quad = lane >> 4;
  f32x4 acc[4][4] = {};
  int sr = tid >> 2, sc = tid & 3;   // staging: row (0..63), 16B chunk (0..3)
  for (int k0 = 0; k0 < H; k0 += 32) {
    const u16* Ac = A + (size_t)(k0 >> 5) * N_NODES * CCOLS;
#pragma unroll
    for (int it = 0; it < 2; ++it) {
      int r = sr + it * 64;
      int grow = mBase + r;
      u32x4 va = {};
      if (grow < N_NODES) va = *(const u32x4*)(Ac + (size_t)grow * CCOLS + sc * 8);
      *(u32x4*)&As[r * 40 + sc * 8] = va;
      u32x4 vb = *(const u32x4*)(BT + (size_t)(nBase + r) * H + k0 + sc * 8);
      *(u32x4*)&Bs[r * 40 + sc * 8] = vb;
    }
    __syncthreads();
    short8 af[4], bfr[4];
#pragma unroll
    for (int i = 0; i < 4; ++i) {
      af[i]  = *(const short8*)&As[(wm + i * 16 + lrow) * 40 + quad * 8];
      bfr[i] = *(const short8*)&Bs[(wn + i * 16 + lrow) * 40 + quad * 8];
    }
#pragma unroll
    for (int mi = 0; mi < 4; ++mi)
#pragma unroll
      for (int ni = 0; ni < 4; ++ni)
        acc[mi][ni] = __builtin_amdgcn_mfma_f32_16x16x32_bf16(af[mi], bfr[ni], acc[mi][ni], 0, 0, 0);
    __syncthreads();
  }
#pragma unroll
  for (int mi = 0; mi < 4; ++mi)
#pragma unroll
    for (int ni = 0; ni < 4; ++ni)
#pragma unroll
      for (int rg = 0; rg < 4; ++rg) {
        int r = mBase + wm + mi * 16 + quad * 4 + rg;  // C/D: row = quad*4+reg
        int c = nBase + wn + ni * 16 + lrow;           //      col = lane&15
        if (r < N_NODES) {
          size_t idx = bidx(r, c);
          float v = (1.0f - beta) * b2f(A[idx]) + beta * acc[mi][ni][rg];
          Hout[idx] = f2b(fmaxf(v, 0.0f));
        }
      }
}

// ---------- projection MFMA GEMM: h0b = h = bf16(x @ projW + b), K=1024 ----------
// 64-row M-tile (grid 782x2 = 1564 blocks, 6/CU) to fix grid-limited occupancy.
// Waves split 1x4 over columns: wm=0, wn=wid*32; acc[4][2].
__global__ __launch_bounds__(256) void k_pgemm(
    const float* __restrict__ X, const u16* __restrict__ BT,
    const float* __restrict__ bias, u16* __restrict__ h0b, u16* __restrict__ h)
{
  __shared__ u16 As[64 * 40];
  __shared__ u16 Bs[128 * 40];
  int tid = threadIdx.x;
  int mBase = blockIdx.x * 64, nBase = blockIdx.y * 128;
  int wid = tid >> 6, lane = tid & 63;
  int wn = wid * 32;               // wave covers cols wn..wn+31 of the 128-col tile
  int lrow = lane & 15, quad = lane >> 4;
  f32x4 acc[4][2] = {};
  int sr = tid >> 2, sc = tid & 3;
  for (int k0 = 0; k0 < DIN; k0 += 32) {
    {   // stage A: 64 rows x 32 k (one pass)
      int grow = mBase + sr;
      float4 fa0 = make_float4(0.f, 0.f, 0.f, 0.f);
      float4 fa1 = make_float4(0.f, 0.f, 0.f, 0.f);
      if (grow < N_NODES) {
        const float* ap = X + (size_t)grow * DIN + k0 + sc * 8;
        fa0 = *(const float4*)ap;
        fa1 = *(const float4*)(ap + 4);
      }
      ushort8_t av;
      av[0] = f2b(fa0.x); av[1] = f2b(fa0.y); av[2] = f2b(fa0.z); av[3] = f2b(fa0.w);
      av[4] = f2b(fa1.x); av[5] = f2b(fa1.y); av[6] = f2b(fa1.z); av[7] = f2b(fa1.w);
      *(ushort8_t*)&As[sr * 40 + sc * 8] = av;
    }
#pragma unroll
    for (int it = 0; it < 2; ++it) {   // stage B: 128 n-rows x 32 k
      int r = sr + it * 64;
      u32x4 vb = *(const u32x4*)(BT + (size_t)(nBase + r) * DIN + k0 + sc * 8);
      *(u32x4*)&Bs[r * 40 + sc * 8] = vb;
    }
    __syncthreads();
    short8 af[4], bfr[2];
#pragma unroll
    for (int i = 0; i < 4; ++i)
      af[i] = *(const short8*)&As[(i * 16 + lrow) * 40 + quad * 8];
#pragma unroll
    for (int i = 0; i < 2; ++i)
      bfr[i] = *(const short8*)&Bs[(wn + i * 16 + lrow) * 40 + quad * 8];
#pragma unroll
    for (int mi = 0; mi < 4; ++mi)
#pragma unroll
      for (int ni = 0; ni < 2; ++ni)
        acc[mi][ni] = __builtin_amdgcn_mfma_f32_16x16x32_bf16(af[mi], bfr[ni], acc[mi][ni], 0, 0, 0);
    __syncthreads();
  }
#pragma unroll
  for (int mi = 0; mi < 4; ++mi)
#pragma unroll
    for (int ni = 0; ni < 2; ++ni)
#pragma unroll
      for (int rg = 0; rg < 4; ++rg) {
        int r = mBase + mi * 16 + quad * 4 + rg;       // C/D: row = quad*4+reg
        int c = nBase + wn + ni * 16 + lrow;           //      col = lane&15
        if (r < N_NODES) {
          size_t idx = bidx(r, c);
          float v = acc[mi][ni][rg] + bias[c];
          u16 bv = f2b(v);
          h0b[idx] = bv;
          h[idx] = bv;
        }
      }
}

// ---------- classifier: out[n, 0..3] = h[n,:] @ clsW + clsb (h blocked bf16) ----------
__global__ __launch_bounds__(256) void k_cls(const u16* __restrict__ h,
    const float* __restrict__ W, const float* __restrict__ b, float* __restrict__ out)
{
  int wid = threadIdx.x >> 6, lane = threadIdx.x & 63;
  int node = blockIdx.x * 4 + wid;
  if (node >= N_NODES) return;
  float a0 = 0, a1 = 0, a2 = 0, a3 = 0;
  for (int t = lane; t < H; t += 64) {
    float hv = b2f(h[bidx(node, t)]);
    a0 += hv * W[t * 4 + 0];
    a1 += hv * W[t * 4 + 1];
    a2 += hv * W[t * 4 + 2];
    a3 += hv * W[t * 4 + 3];
  }
#pragma unroll
  for (int off = 32; off > 0; off >>= 1) {
    a0 += __shfl_down(a0, off);
    a1 += __shfl_down(a1, off);
    a2 += __shfl_down(a2, off);
    a3 += __shfl_down(a3, off);
  }
  if (lane == 0) {
    float4 o;
    o.x = a0 + b[0];
    o.y = a1 + b[1];
    o.z = a2 + b[2];
    o.w = a3 + b[3];
    *(float4*)(out + (size_t)node * 4) = o;
  }
}

extern "C" void kernel_launch(void* const* d_in, const int* in_sizes, int n_in,
                              void* d_out, int out_size, void* d_ws, size_t ws_size,
                              hipStream_t stream) {
  (void)in_sizes; (void)n_in; (void)out_size; (void)ws_size;
  const float* x     = (const float*)d_in[0];
  const int*   ei    = (const int*)d_in[1];
  const float* projW = (const float*)d_in[2];
  const float* projB = (const float*)d_in[3];
  const float* wts   = (const float*)d_in[4];
  const float* clsW  = (const float*)d_in[5];
  const float* clsB  = (const float*)d_in[6];
  float* out = (float*)d_out;

  char* ws = (char*)d_ws;
  size_t off = 0;
  auto alloc = [&](size_t bytes) -> void* {
    void* p = ws + off;
    off = (off + bytes + 255) & ~(size_t)255;
    return p;
  };
  int*   cntcur = (int*)alloc((size_t)N_NODES * 2 * 4);
  int*   cnt    = cntcur;
  int*   cursor = cntcur + N_NODES;
  int*   offs   = (int*)alloc((size_t)(N_NODES + 1) * 4);
  float* dinv   = (float*)alloc((size_t)N_NODES * 4);
  unsigned* ew  = (unsigned*)alloc((size_t)N_EDGES * 4);
  u16*   WT     = (u16*)alloc((size_t)L_LAYERS * H * H * 2);
  u16*   BTp    = (u16*)alloc((size_t)H * DIN * 2);
  u16*   h0b    = (u16*)alloc((size_t)N_NODES * H * 2);
  u16*   sb     = (u16*)alloc((size_t)N_NODES * H * 2);
  u16*   h      = (u16*)alloc((size_t)N_NODES * H * 2);

  const int* src = ei;
  const int* dst = ei + N_EDGES;

  k_zero<<<(N_NODES * 2 + 255) / 256, 256, 0, stream>>>(cntcur, N_NODES * 2);
  k_count<<<(N_EDGES + 255) / 256, 256, 0, stream>>>(dst, cnt);
  k_dinv<<<(N_NODES + 255) / 256, 256, 0, stream>>>(cnt, dinv);
  k_scan<<<1, 1024, 0, stream>>>(cnt, offs);
  k_scatter<<<(N_EDGES + 255) / 256, 256, 0, stream>>>(src, dst, offs, cursor, dinv, ew);
  k_wtr<<<dim3(H / 32, H / 32, L_LAYERS), dim3(32, 8), 0, stream>>>(wts, WT);
  k_trP<<<dim3(H / 32, DIN / 32), dim3(32, 8), 0, stream>>>(projW, BTp);

  // projection: h0b (bf16) and h (bf16) = bf16(x @ projW + b), via MFMA
  k_pgemm<<<dim3((N_NODES + 63) / 64, H / 128), 256, 0, stream>>>(x, BTp, projB, h0b, h);

  dim3 ggrid((N_NODES + 127) / 128, H / 128);
  const int spmm_blocks = ((N_NODES + 15) / 16) * NCHUNK;
  for (int l = 0; l < L_LAYERS; ++l) {
    k_spmm<<<spmm_blocks, 256, 0, stream>>>(h, h0b, offs, ew, dinv, sb);
    float beta = logf(0.5f / (float)(l + 1) + 1.0f);
    k_gemm<<<ggrid, 256, 0, stream>>>(sb, WT + (size_t)l * H * H, h, beta);
  }
  k_cls<<<(N_NODES + 3) / 4, 256, 0, stream>>>(h, clsW, clsB, out);
}